// Round 8
// baseline (385.086 us; speedup 1.0000x reference)
//
#include <hip/hip_runtime.h>
#include <hip/hip_fp16.h>

#define NN 40000
#define NE 640000
#define DD 128
#define NW (NE/64)   // 10000 waves of 64 edges

typedef _Float16 half8 __attribute__((ext_vector_type(8)));
typedef float f32x4 __attribute__((ext_vector_type(4)));

__device__ __forceinline__ float silu_f(float x){
  return x * __builtin_amdgcn_rcpf(1.f + __expf(-x));
}

__device__ __forceinline__ half8 cvt_h8(float4 a, float4 b){
  half8 r;
  r[0]=(_Float16)a.x; r[1]=(_Float16)a.y; r[2]=(_Float16)a.z; r[3]=(_Float16)a.w;
  r[4]=(_Float16)b.x; r[5]=(_Float16)b.y; r[6]=(_Float16)b.z; r[7]=(_Float16)b.w;
  return r;
}

__device__ __forceinline__ void atom_pk_f16(_Float16* p, unsigned v){
  asm volatile("global_atomic_pk_add_f16 %0, %1, off" :: "v"(p), "v"(v));
}

// ---------------- sort-by-dst infrastructure ----------------
// hist + agg zeroing fused (exactly NE threads; agg = NN*DD f16 = 640000 uint4)
__global__ void k_hist(const int* __restrict__ ei, int* __restrict__ counts,
                       uint4* __restrict__ aggz){
  int e = blockIdx.x*256 + threadIdx.x;
  if (e < NE){
    atomicAdd(&counts[ei[NE + e]], 1);
    aggz[e] = make_uint4(0,0,0,0);
  }
}

__global__ __launch_bounds__(1024)
void k_scanA(const int* __restrict__ counts, int* __restrict__ woff,
             int* __restrict__ bsum){
  __shared__ int wsum[16];
  const int tid = threadIdx.x, lane = tid & 63, wv = tid >> 6;
  int i = blockIdx.x*1024 + tid;
  int v = (i < NN) ? counts[i] : 0;
  int s = v;
  #pragma unroll
  for (int d = 1; d < 64; d <<= 1){
    int t = __shfl_up(s, d, 64);
    if (lane >= d) s += t;
  }
  if (lane == 63) wsum[wv] = s;
  __syncthreads();
  if (tid < 16){
    int t = wsum[tid];
    #pragma unroll
    for (int d = 1; d < 16; d <<= 1){
      int u = __shfl_up(t, d, 64);
      if (tid >= d) t += u;
    }
    wsum[tid] = t;
  }
  __syncthreads();
  int wbase = (wv == 0) ? 0 : wsum[wv-1];
  if (i < NN) woff[i] = wbase + s - v;        // block-local exclusive
  if (tid == 1023) bsum[blockIdx.x] = wbase + s;
}

// scanB folded in: every wave redundantly scans the 40 block totals
__global__ __launch_bounds__(1024)
void k_scanC(int* __restrict__ woff, const int* __restrict__ bsum){
  const int lane = threadIdx.x & 63;
  int v = (lane < 40) ? bsum[lane] : 0;
  int s = v;
  #pragma unroll
  for (int d = 1; d < 64; d <<= 1){
    int t = __shfl_up(s, d, 64);
    if (lane >= d) s += t;
  }
  int boff = (blockIdx.x == 0) ? 0 : __shfl(s, blockIdx.x - 1, 64);
  int i = blockIdx.x*1024 + threadIdx.x;
  if (i < NN) woff[i] += boff;
}

// packed (src<<16)|dst  (both < 65536)
__global__ void k_scatter(const int* __restrict__ ei, int* __restrict__ woff,
                          unsigned* __restrict__ sdp){
  int e = blockIdx.x*256 + threadIdx.x;
  if (e < NE){
    int s = ei[e];
    int d = ei[NE + e];
    int p = atomicAdd(&woff[d], 1);
    sdp[p] = ((unsigned)s << 16) | (unsigned)d;
  }
}

// ---------------------------------------------------------------------------
// Weight transpose to f16 [ch][k] in global + counts zeroing (runs pre-hist)
// ---------------------------------------------------------------------------
__global__ void k_wt(const float* __restrict__ We1, const float* __restrict__ Wh1,
                     const float* __restrict__ Wh2,
                     _Float16* __restrict__ We1t, _Float16* __restrict__ Wh1t,
                     _Float16* __restrict__ Wh2t, int* __restrict__ counts){
  int i = blockIdx.x*256 + threadIdx.x;    // 32768 threads
  if (i < 128*256){
    int ch = i >> 8, k = i & 255;
    We1t[i] = (_Float16)We1[k*128 + ch];
    Wh1t[i] = (_Float16)Wh1[k*128 + ch];
  }
  if (i < 128*128){
    int ch = i >> 7, k = i & 127;
    Wh2t[i] = (_Float16)Wh2[k*128 + ch];
  }
  for (int c = i; c < NN; c += 32768) counts[c] = 0;
}

// ---------------------------------------------------------------------------
// G-precompute, 16 nodes/wave, B-fragments from global We1t. No LDS.
// ---------------------------------------------------------------------------
__global__ __launch_bounds__(256) __attribute__((amdgpu_waves_per_eu(3,4)))
void k_gpre(const float* __restrict__ h, const _Float16* __restrict__ We1t,
            const float* __restrict__ be1,
            _Float16* __restrict__ g1, _Float16* __restrict__ g2)
{
  const int tid = threadIdx.x, lane = tid & 63, w = tid >> 6;
  const int q = lane & 15, g = lane >> 4;
  const int base = (blockIdx.x*4 + w) * 16;
  float be1r[8];
  #pragma unroll
  for (int nt=0; nt<8; nt++) be1r[nt] = be1[nt*16+q];

  half8 a[4];
  #pragma unroll
  for (int kk=0; kk<4; kk++){
    const float* rp = h + (size_t)(base+q)*DD + kk*32 + g*8;
    a[kk] = cvt_h8(*(const float4*)rp, *(const float4*)(rp+4));
  }
  f32x4 ac1[8] = {}, ac2[8] = {};
  #pragma unroll
  for (int kk=0; kk<4; kk++){
    #pragma unroll
    for (int nt=0; nt<8; nt++){
      half8 b1 = *(const half8*)&We1t[(nt*16+q)*256 + kk*32 + g*8];
      half8 b2 = *(const half8*)&We1t[(nt*16+q)*256 + 128 + kk*32 + g*8];
      ac1[nt] = __builtin_amdgcn_mfma_f32_16x16x32_f16(a[kk], b1, ac1[nt], 0,0,0);
      ac2[nt] = __builtin_amdgcn_mfma_f32_16x16x32_f16(a[kk], b2, ac2[nt], 0,0,0);
    }
  }
  #pragma unroll
  for (int r=0;r<4;r++){
    int node = base + 4*g + r;
    #pragma unroll
    for (int nt=0; nt<8; nt++){
      g1[(size_t)node*DD + nt*16+q] = (_Float16)(ac1[nt][r] + be1r[nt]);
      g2[(size_t)node*DD + nt*16+q] = (_Float16)ac2[nt][r];
    }
  }
}

// ---------------------------------------------------------------------------
// Edge kernel, dst-sorted. 1024 thr = 16 waves (4/SIMD), VGPR cap 128.
// g1[src] prefetched (random gather); g2[dst] inline (dst-sorted -> L1-hot).
// Packed-f16 silu on L1 path. Segment-reduced agg flush (plain stores
// interior, pk-atomics at wave boundaries). LDS: 64K weights + 64K mbuf.
// ---------------------------------------------------------------------------
__global__ __launch_bounds__(1024) __attribute__((amdgpu_waves_per_eu(4,4)))
void egnn_edge(const _Float16* __restrict__ g1, const _Float16* __restrict__ g2,
               const float* __restrict__ x,
               const unsigned* __restrict__ sdp,
               const float* __restrict__ We1,
               const float* __restrict__ We2, const float* __restrict__ be2,
               const float* __restrict__ Wx1, const float* __restrict__ bx1,
               const float* __restrict__ Wx2, const float* __restrict__ bx2,
               _Float16* __restrict__ agg, float* __restrict__ cwb)
{
  __shared__ __align__(16) _Float16 W2t[128*128];    // 32 KB
  __shared__ __align__(16) _Float16 Wxt[128*128];    // 32 KB
  __shared__ __align__(16) _Float16 mbuf[16][16*128];// 64 KB
  __shared__ __align__(16) _Float16 w1l_lds[128];

  const int tid = threadIdx.x;
  for (int i = tid; i < 128*128; i += 1024){
    int ch = i & 127, k = i >> 7;
    int sw = (ch & 15) << 3;
    W2t[ch*128 + (k ^ sw)] = (_Float16)We2[k*128 + ch];
    Wxt[ch*128 + (k ^ sw)] = (_Float16)Wx1[k*128 + ch];
  }
  if (tid < 128) w1l_lds[tid] = (_Float16)We1[256*128 + tid];
  const int lane = tid & 63;
  const int w    = tid >> 6;
  const int q    = lane & 15;
  const int g    = lane >> 4;
  float be2r[8], bx1r[8], wx2r[8];
  #pragma unroll
  for (int nt = 0; nt < 8; nt++){
    int ch = nt*16 + q;
    be2r[nt] = be2[ch];
    bx1r[nt] = bx1[ch];
    wx2r[nt] = Wx2[ch];
  }
  const float bx2s = bx2[0];
  _Float16* mb = mbuf[w];
  __syncthreads();

  const int gw = blockIdx.x*16 + w;          // grid = NW/16 exactly

  half8 w1l_h[4];
  #pragma unroll
  for (int kk=0; kk<4; kk++)
    w1l_h[kk] = *(const half8*)&w1l_lds[kk*32 + g*8];

  // this lane's edge (dst-sorted)
  const unsigned sv = sdp[gw*64 + lane];
  const int esrc = (int)(sv >> 16);
  const int edst = (int)(sv & 0xffffu);
  float r0 = x[esrc*3+0] - x[edst*3+0];
  float r1 = x[esrc*3+1] - x[edst*3+1];
  float r2 = x[esrc*3+2] - x[edst*3+2];
  float d2 = r0*r0 + r1*r1 + r2*r2;

  // wave-boundary segment info
  const int first_dst = __shfl(edst, 0, 64);
  const int last_dst  = __shfl(edst, 63, 64);
  const bool prev_spill = (gw > 0)    && ((int)(sdp[gw*64 - 1] & 0xffffu) == first_dst);
  const bool next_spill = (gw < NW-1) && ((int)(sdp[gw*64 + 64] & 0xffffu) == last_dst);

  // per-mt MFMA-operand indices (hoisted)
  int srcq[4], dstq[4];
  __half2 d2h[4];
  #pragma unroll
  for (int mt=0; mt<4; mt++){
    srcq[mt] = __shfl(esrc, mt*16 + q, 64);
    dstq[mt] = __shfl(edst, mt*16 + q, 64);
    d2h[mt]  = __float2half2_rn(__shfl(d2, mt*16 + q, 64));
  }
  const __half2 one2 = __float2half2_rn(1.f);

  // cross-mt segment accumulator (channel pair 2*lane, 2*lane+1)
  float fa0 = 0.f, fa1 = 0.f;
  int   fdprev = first_dst;
  bool  seg_first = true;

  // prefetch double buffer for the random src gather only
  uint4 pa1[4], pb1[4];
  #pragma unroll
  for (int kk=0; kk<4; kk++)
    pa1[kk] = *(const uint4*)(g1 + (size_t)srcq[0]*DD + kk*32 + g*8);

  #pragma unroll
  for (int mt=0; mt<4; mt++){
    uint4 (&cu1)[4] = (mt&1) ? pb1 : pa1;
    uint4 (&nu1)[4] = (mt&1) ? pa1 : pb1;
    if (mt < 3){
      #pragma unroll
      for (int kk=0; kk<4; kk++)
        nu1[kk] = *(const uint4*)(g1 + (size_t)srcq[mt+1]*DD + kk*32 + g*8);
    }

    // ---- phi_e L1: z = G1[src]+G2[dst]+d2*w1l, silu — packed f16 ----
    half8 a[4];
    #pragma unroll
    for (int kk=0; kk<4; kk++){
      uint4 cu2 = *(const uint4*)(g2 + (size_t)dstq[mt]*DD + kk*32 + g*8);
      uint4 w4 = __builtin_bit_cast(uint4, w1l_h[kk]);
      unsigned uu1[4] = {cu1[kk].x, cu1[kk].y, cu1[kk].z, cu1[kk].w};
      unsigned uu2[4] = {cu2.x, cu2.y, cu2.z, cu2.w};
      unsigned ww[4]  = {w4.x, w4.y, w4.z, w4.w};
      unsigned zz[4];
      #pragma unroll
      for (int p2=0; p2<4; p2++){
        __half2 z = __hadd2(__builtin_bit_cast(__half2, uu1[p2]),
                            __builtin_bit_cast(__half2, uu2[p2]));
        z = __hfma2(d2h[mt], __builtin_bit_cast(__half2, ww[p2]), z);
        __half2 e   = h2exp(__hneg2(z));
        __half2 den = __hadd2(e, one2);
        __half2 m   = __hmul2(z, h2rcp(den));
        zz[p2] = __builtin_bit_cast(unsigned, m);
      }
      uint4 t; t.x = zz[0]; t.y = zz[1]; t.z = zz[2]; t.w = zz[3];
      a[kk] = __builtin_bit_cast(half8, t);
    }

    // ---- phi_e layer 2 ----
    f32x4 acc2[8] = {};
    #pragma unroll
    for (int kk=0; kk<4; kk++){
      #pragma unroll
      for (int nt=0; nt<8; nt++){
        half8 b = *(const half8*)&W2t[(nt*16+q)*128 + ((kk*32+g*8) ^ (q<<3))];
        acc2[nt] = __builtin_amdgcn_mfma_f32_16x16x32_f16(a[kk], b, acc2[nt], 0,0,0);
      }
    }
    // silu -> m, transpose into mbuf
    #pragma unroll
    for (int nt=0; nt<8; nt++){
      #pragma unroll
      for (int r=0;r<4;r++){
        float s = silu_f(acc2[nt][r] + be2r[nt]);
        int el = 4*g + r;
        mb[el*128 + ((nt*16+q) ^ (el<<3))] = (_Float16)s;
      }
    }
    // ---- phi_x layer 1 ----
    f32x4 acc3[8] = {};
    #pragma unroll
    for (int kk=0; kk<4; kk++){
      half8 am = *(const half8*)&mb[q*128 + ((kk*32+g*8) ^ (q<<3))];
      #pragma unroll
      for (int nt=0; nt<8; nt++){
        half8 b = *(const half8*)&Wxt[(nt*16+q)*128 + ((kk*32+g*8) ^ (q<<3))];
        acc3[nt] = __builtin_amdgcn_mfma_f32_16x16x32_f16(am, b, acc3[nt], 0,0,0);
      }
    }
    // ---- coord_w reduce + per-edge cw store ----
    float part[4] = {0.f,0.f,0.f,0.f};
    #pragma unroll
    for (int nt=0; nt<8; nt++){
      #pragma unroll
      for (int r=0;r<4;r++)
        part[r] += silu_f(acc3[nt][r] + bx1r[nt]) * wx2r[nt];
    }
    #pragma unroll
    for (int m=1; m<16; m<<=1){
      #pragma unroll
      for (int r=0;r<4;r++) part[r] += __shfl_xor(part[r], m, 64);
    }
    {
      float cw = part[0];
      if (q==1) cw = part[1]; else if (q==2) cw = part[2]; else if (q==3) cw = part[3];
      if (q < 4) cwb[gw*64 + mt*16 + 4*g + q] = cw + bx2s;
    }
    // ---- segment-reduced agg flush ----
    {
      unsigned mv[16];
      #pragma unroll
      for (int e2=0; e2<16; e2++)
        mv[e2] = *(const unsigned*)&mb[e2*128 + ((2*lane) ^ (e2<<3))];
      int dv[16];
      #pragma unroll
      for (int e2=0; e2<16; e2++) dv[e2] = __shfl(edst, mt*16 + e2, 64);
      #pragma unroll
      for (int e2=0; e2<16; e2++){
        if (dv[e2] != fdprev){        // wave-uniform branch
          __half2 hv; hv.x = __float2half(fa0); hv.y = __float2half(fa1);
          _Float16* p = agg + (size_t)fdprev*DD + 2*lane;
          if (seg_first && prev_spill) atom_pk_f16(p, __builtin_bit_cast(unsigned, hv));
          else                         *(__half2*)p = hv;
          fa0 = 0.f; fa1 = 0.f; fdprev = dv[e2]; seg_first = false;
        }
        __half2 mvv = __builtin_bit_cast(__half2, mv[e2]);
        fa0 += __half2float(mvv.x);
        fa1 += __half2float(mvv.y);
      }
    }
  }
  // final flush
  {
    __half2 hv; hv.x = __float2half(fa0); hv.y = __float2half(fa1);
    _Float16* p = agg + (size_t)fdprev*DD + 2*lane;
    if ((seg_first && prev_spill) || next_spill) atom_pk_f16(p, __builtin_bit_cast(unsigned, hv));
    else                                         *(__half2*)p = hv;
  }
}

// ---------------------------------------------------------------------------
// Node kernel: 16 nodes/wave, B-fragments from global Wh1t/Wh2t.
// ---------------------------------------------------------------------------
__global__ __launch_bounds__(256) __attribute__((amdgpu_waves_per_eu(3,4)))
void egnn_node(const float* __restrict__ h, const _Float16* __restrict__ agg,
               const _Float16* __restrict__ Wh1t, const _Float16* __restrict__ Wh2t,
               const float* __restrict__ bh1, const float* __restrict__ bh2,
               const float* __restrict__ gam, const float* __restrict__ bet,
               float* __restrict__ hout)
{
  __shared__ __align__(16) _Float16 mbuf[4][16*128];  // 16 KB
  const int tid = threadIdx.x, lane = tid & 63, w = tid >> 6;
  const int q = lane & 15, g = lane >> 4;
  const int base = (blockIdx.x*4 + w) * 16;
  float bh1r[8], bh2r[8], gr[8], br[8];
  #pragma unroll
  for (int nt=0; nt<8; nt++){
    int ch = nt*16+q;
    bh1r[nt]=bh1[ch]; bh2r[nt]=bh2[ch]; gr[nt]=gam[ch]; br[nt]=bet[ch];
  }
  _Float16* mb = mbuf[w];

  f32x4 ac1[8] = {};
  #pragma unroll
  for (int kk=0; kk<8; kk++){
    half8 a;
    if (kk < 4){
      const float* rp = h + (size_t)(base+q)*DD + kk*32 + g*8;
      a = cvt_h8(*(const float4*)rp, *(const float4*)(rp+4));
    } else {
      a = *(const half8*)(agg + (size_t)(base+q)*DD + (kk-4)*32 + g*8);
    }
    #pragma unroll
    for (int nt=0; nt<8; nt++){
      half8 b = *(const half8*)&Wh1t[(nt*16+q)*256 + kk*32 + g*8];
      ac1[nt] = __builtin_amdgcn_mfma_f32_16x16x32_f16(a, b, ac1[nt], 0,0,0);
    }
  }
  #pragma unroll
  for (int nt=0; nt<8; nt++){
    #pragma unroll
    for (int r=0;r<4;r++){
      float s = silu_f(ac1[nt][r] + bh1r[nt]);
      int el = 4*g + r;
      mb[el*128 + ((nt*16+q) ^ (el<<3))] = (_Float16)s;
    }
  }
  f32x4 ac2[8] = {};
  #pragma unroll
  for (int kk=0; kk<4; kk++){
    half8 am = *(const half8*)&mb[q*128 + ((kk*32+g*8) ^ (q<<3))];
    #pragma unroll
    for (int nt=0; nt<8; nt++){
      half8 b = *(const half8*)&Wh2t[(nt*16+q)*128 + kk*32 + g*8];
      ac2[nt] = __builtin_amdgcn_mfma_f32_16x16x32_f16(am, b, ac2[nt], 0,0,0);
    }
  }
  #pragma unroll
  for (int r=0;r<4;r++){
    int node = base + 4*g + r;
    float hv[8]; float s1=0.f, s2=0.f;
    #pragma unroll
    for (int nt=0; nt<8; nt++){
      float v = ac2[nt][r] + bh2r[nt] + h[(size_t)node*DD + nt*16 + q];
      hv[nt]=v; s1 += v; s2 += v*v;
    }
    #pragma unroll
    for (int m=1;m<16;m<<=1){ s1 += __shfl_xor(s1,m,64); s2 += __shfl_xor(s2,m,64); }
    float mu  = s1 * (1.f/128.f);
    float var = s2 * (1.f/128.f) - mu*mu;
    float rs  = rsqrtf(var + 1e-5f);
    #pragma unroll
    for (int nt=0; nt<8; nt++)
      hout[(size_t)node*DD + nt*16 + q] = (hv[nt]-mu)*rs*gr[nt] + br[nt];
  }
}

// ---------------------------------------------------------------------------
// Coordinate update: 16 lanes per node, segment-mean of rel*cw. No atomics.
// ---------------------------------------------------------------------------
__global__ __launch_bounds__(256)
void k_coord(const float* __restrict__ x, const float* __restrict__ cwb,
             const unsigned* __restrict__ sdp, const int* __restrict__ counts,
             const int* __restrict__ woff, float* __restrict__ xout)
{
  const int tid = threadIdx.x, lane = tid & 63, w = tid >> 6;
  const int sub = lane >> 4, j0 = lane & 15;
  const int n = (blockIdx.x*4 + w)*4 + sub;
  if (n >= NN) return;
  const int cnt = counts[n];
  const int s = woff[n] - cnt;      // woff is end-offset after k_scatter
  float xd0 = x[n*3+0], xd1 = x[n*3+1], xd2 = x[n*3+2];
  float s0=0.f, s1=0.f, s2=0.f;
  for (int j = j0; j < cnt; j += 16){
    int e = s + j;
    float cw = cwb[e];
    int src = (int)(sdp[e] >> 16);
    s0 += (x[src*3+0]-xd0)*cw;
    s1 += (x[src*3+1]-xd1)*cw;
    s2 += (x[src*3+2]-xd2)*cw;
  }
  #pragma unroll
  for (int m=1; m<16; m<<=1){
    s0 += __shfl_xor(s0, m, 64);
    s1 += __shfl_xor(s1, m, 64);
    s2 += __shfl_xor(s2, m, 64);
  }
  if (j0 == 0){
    float inv = __builtin_amdgcn_rcpf((float)(cnt > 1 ? cnt : 1));
    xout[n*3+0] = xd0 + s0*inv;
    xout[n*3+1] = xd1 + s1*inv;
    xout[n*3+2] = xd2 + s2*inv;
  }
}

extern "C" void kernel_launch(void* const* d_in, const int* in_sizes, int n_in,
                              void* d_out, int out_size, void* d_ws, size_t ws_size,
                              hipStream_t stream){
  const float* h   = (const float*)d_in[0];
  const float* x   = (const float*)d_in[1];
  const int*   ei  = (const int*)d_in[2];
  const float* We1 = (const float*)d_in[4];
  const float* be1 = (const float*)d_in[5];
  const float* We2 = (const float*)d_in[6];
  const float* be2 = (const float*)d_in[7];
  const float* Wx1 = (const float*)d_in[8];
  const float* bx1 = (const float*)d_in[9];
  const float* Wx2 = (const float*)d_in[10];
  const float* bx2 = (const float*)d_in[11];
  const float* Wh1 = (const float*)d_in[12];
  const float* bh1 = (const float*)d_in[13];
  const float* Wh2 = (const float*)d_in[14];
  const float* bh2 = (const float*)d_in[15];
  const float* gam = (const float*)d_in[16];
  const float* bet = (const float*)d_in[17];

  float* hout = (float*)d_out;
  float* xout = hout + (size_t)NN*DD;

  // ws layout (16B-aligned), ~36.4 MB
  char* p = (char*)d_ws;
  _Float16* agg  = (_Float16*)p;  p += (size_t)NN*DD*2;   // 10.24 MB
  _Float16* g1   = (_Float16*)p;  p += (size_t)NN*DD*2;   // 10.24 MB
  _Float16* g2   = (_Float16*)p;  p += (size_t)NN*DD*2;   // 10.24 MB
  int* counts    = (int*)p;       p += (size_t)NN*4;      // 0.16 MB
  int* woff      = (int*)p;       p += (size_t)NN*4;      // 0.16 MB
  unsigned* sdp  = (unsigned*)p;  p += (size_t)NE*4;      // 2.56 MB
  float* cwb     = (float*)p;     p += (size_t)NE*4;      // 2.56 MB
  _Float16* We1t = (_Float16*)p;  p += (size_t)128*256*2; // 64 KB
  _Float16* Wh1t = (_Float16*)p;  p += (size_t)128*256*2; // 64 KB
  _Float16* Wh2t = (_Float16*)p;  p += (size_t)128*128*2; // 32 KB
  int* bsum      = (int*)p;       p += 64*4;

  k_wt<<<128, 256, 0, stream>>>(We1, Wh1, Wh2, We1t, Wh1t, Wh2t, counts);
  k_hist<<<(NE+255)/256, 256, 0, stream>>>(ei, counts, (uint4*)agg);
  k_scanA<<<(NN+1023)/1024, 1024, 0, stream>>>(counts, woff, bsum);
  k_scanC<<<(NN+1023)/1024, 1024, 0, stream>>>(woff, bsum);
  k_scatter<<<(NE+255)/256, 256, 0, stream>>>(ei, woff, sdp);
  k_gpre<<<NN/64, 256, 0, stream>>>(h, We1t, be1, g1, g2);
  egnn_edge<<<NW/16, 1024, 0, stream>>>(g1, g2, x, sdp, We1,
                                        We2, be2, Wx1, bx1, Wx2, bx2,
                                        agg, cwb);
  egnn_node<<<NN/64, 256, 0, stream>>>(h, agg, Wh1t, Wh2t, bh1, bh2,
                                       gam, bet, hout);
  k_coord<<<NN/16, 256, 0, stream>>>(x, cwb, sdp, counts, woff, xout);
}

// Round 9
// 330.907 us; speedup vs baseline: 1.1637x; 1.1637x over previous
//
#include <hip/hip_runtime.h>
#include <hip/hip_fp16.h>

#define NN 40000
#define NE 640000
#define DD 128
#define NW (NE/64)   // 10000 waves of 64 edges

typedef _Float16 half8 __attribute__((ext_vector_type(8)));
typedef float f32x4 __attribute__((ext_vector_type(4)));

__device__ __forceinline__ float silu_f(float x){
  return x * __builtin_amdgcn_rcpf(1.f + __expf(-x));
}

__device__ __forceinline__ half8 cvt_h8(float4 a, float4 b){
  half8 r;
  r[0]=(_Float16)a.x; r[1]=(_Float16)a.y; r[2]=(_Float16)a.z; r[3]=(_Float16)a.w;
  r[4]=(_Float16)b.x; r[5]=(_Float16)b.y; r[6]=(_Float16)b.z; r[7]=(_Float16)b.w;
  return r;
}

__device__ __forceinline__ void atom_pk_f16(_Float16* p, unsigned v){
  asm volatile("global_atomic_pk_add_f16 %0, %1, off" :: "v"(p), "v"(v));
}

// ---------------- sort-by-dst infrastructure ----------------
// hist + agg zeroing fused (exactly NE threads; agg = NN*DD f16 = 640000 uint4)
__global__ void k_hist(const int* __restrict__ ei, int* __restrict__ counts,
                       uint4* __restrict__ aggz){
  int e = blockIdx.x*256 + threadIdx.x;
  if (e < NE){
    atomicAdd(&counts[ei[NE + e]], 1);
    aggz[e] = make_uint4(0,0,0,0);
  }
}

__global__ __launch_bounds__(1024)
void k_scanA(const int* __restrict__ counts, int* __restrict__ woff,
             int* __restrict__ bsum){
  __shared__ int wsum[16];
  const int tid = threadIdx.x, lane = tid & 63, wv = tid >> 6;
  int i = blockIdx.x*1024 + tid;
  int v = (i < NN) ? counts[i] : 0;
  int s = v;
  #pragma unroll
  for (int d = 1; d < 64; d <<= 1){
    int t = __shfl_up(s, d, 64);
    if (lane >= d) s += t;
  }
  if (lane == 63) wsum[wv] = s;
  __syncthreads();
  if (tid < 16){
    int t = wsum[tid];
    #pragma unroll
    for (int d = 1; d < 16; d <<= 1){
      int u = __shfl_up(t, d, 64);
      if (tid >= d) t += u;
    }
    wsum[tid] = t;
  }
  __syncthreads();
  int wbase = (wv == 0) ? 0 : wsum[wv-1];
  if (i < NN) woff[i] = wbase + s - v;        // block-local exclusive
  if (tid == 1023) bsum[blockIdx.x] = wbase + s;
}

// scanB folded in: every wave redundantly scans the 40 block totals
__global__ __launch_bounds__(1024)
void k_scanC(int* __restrict__ woff, const int* __restrict__ bsum){
  const int lane = threadIdx.x & 63;
  int v = (lane < 40) ? bsum[lane] : 0;
  int s = v;
  #pragma unroll
  for (int d = 1; d < 64; d <<= 1){
    int t = __shfl_up(s, d, 64);
    if (lane >= d) s += t;
  }
  int boff = (blockIdx.x == 0) ? 0 : __shfl(s, blockIdx.x - 1, 64);
  int i = blockIdx.x*1024 + threadIdx.x;
  if (i < NN) woff[i] += boff;
}

// ---------------------------------------------------------------------------
// Weight transpose to f16 [ch][k] in global + counts zeroing (runs pre-hist)
// ---------------------------------------------------------------------------
__global__ void k_wt(const float* __restrict__ We1, const float* __restrict__ Wh1,
                     const float* __restrict__ Wh2,
                     _Float16* __restrict__ We1t, _Float16* __restrict__ Wh1t,
                     _Float16* __restrict__ Wh2t, int* __restrict__ counts){
  int i = blockIdx.x*256 + threadIdx.x;    // 32768 threads
  if (i < 128*256){
    int ch = i >> 8, k = i & 255;
    We1t[i] = (_Float16)We1[k*128 + ch];
    Wh1t[i] = (_Float16)Wh1[k*128 + ch];
  }
  if (i < 128*128){
    int ch = i >> 7, k = i & 127;
    Wh2t[i] = (_Float16)Wh2[k*128 + ch];
  }
  for (int c = i; c < NN; c += 32768) counts[c] = 0;
}

// ---------------------------------------------------------------------------
// FUSED: scatter (blocks 0..2499) + G-precompute (blocks 2500..3124).
// Independent phases co-scheduled: scatter is atomic/latency-bound, gpre is
// MFMA-bound -> overlap fills the machine.
// ---------------------------------------------------------------------------
__global__ __launch_bounds__(256)
void k_scatgpre(const int* __restrict__ ei, int* __restrict__ woff,
                unsigned* __restrict__ sdp,
                const float* __restrict__ h, const _Float16* __restrict__ We1t,
                const float* __restrict__ be1,
                _Float16* __restrict__ g1, _Float16* __restrict__ g2)
{
  if (blockIdx.x < NE/256){
    int e = blockIdx.x*256 + threadIdx.x;
    int s = ei[e];
    int d = ei[NE + e];
    int p = atomicAdd(&woff[d], 1);
    sdp[p] = ((unsigned)s << 16) | (unsigned)d;
    return;
  }
  const int b = blockIdx.x - NE/256;
  const int tid = threadIdx.x, lane = tid & 63, w = tid >> 6;
  const int q = lane & 15, g = lane >> 4;
  const int base = (b*4 + w) * 16;
  float be1r[8];
  #pragma unroll
  for (int nt=0; nt<8; nt++) be1r[nt] = be1[nt*16+q];

  half8 a[4];
  #pragma unroll
  for (int kk=0; kk<4; kk++){
    const float* rp = h + (size_t)(base+q)*DD + kk*32 + g*8;
    a[kk] = cvt_h8(*(const float4*)rp, *(const float4*)(rp+4));
  }
  f32x4 ac1[8] = {}, ac2[8] = {};
  #pragma unroll
  for (int kk=0; kk<4; kk++){
    #pragma unroll
    for (int nt=0; nt<8; nt++){
      half8 b1 = *(const half8*)&We1t[(nt*16+q)*256 + kk*32 + g*8];
      half8 b2 = *(const half8*)&We1t[(nt*16+q)*256 + 128 + kk*32 + g*8];
      ac1[nt] = __builtin_amdgcn_mfma_f32_16x16x32_f16(a[kk], b1, ac1[nt], 0,0,0);
      ac2[nt] = __builtin_amdgcn_mfma_f32_16x16x32_f16(a[kk], b2, ac2[nt], 0,0,0);
    }
  }
  #pragma unroll
  for (int r=0;r<4;r++){
    int node = base + 4*g + r;
    #pragma unroll
    for (int nt=0; nt<8; nt++){
      g1[(size_t)node*DD + nt*16+q] = (_Float16)(ac1[nt][r] + be1r[nt]);
      g2[(size_t)node*DD + nt*16+q] = (_Float16)ac2[nt][r];
    }
  }
}

// ---------------------------------------------------------------------------
// Edge kernel, dst-sorted. 768 thr = 12 waves (3/SIMD, LDS-bound).
// __launch_bounds__(768,3): 3 waves/EU declared -> VGPR cap ~170, keep
// prefetch buffers live. Software-pipelined mt loop (double-buffered g1/g2
// gathers); packed-f16 silu on L1 path; segment-reduced agg flush.
// LDS: 32K W2t + 32K Wxt + 48K mbuf + 256B = 112.3 KB.
// ---------------------------------------------------------------------------
__global__ __launch_bounds__(768, 3)
void egnn_edge(const _Float16* __restrict__ g1, const _Float16* __restrict__ g2,
               const float* __restrict__ x,
               const unsigned* __restrict__ sdp,
               const float* __restrict__ We1,
               const float* __restrict__ We2, const float* __restrict__ be2,
               const float* __restrict__ Wx1, const float* __restrict__ bx1,
               const float* __restrict__ Wx2, const float* __restrict__ bx2,
               _Float16* __restrict__ agg, float* __restrict__ cwb)
{
  __shared__ __align__(16) _Float16 W2t[128*128];    // 32 KB
  __shared__ __align__(16) _Float16 Wxt[128*128];    // 32 KB
  __shared__ __align__(16) _Float16 mbuf[12][16*128];// 48 KB
  __shared__ __align__(16) _Float16 w1l_lds[128];

  const int tid = threadIdx.x;
  for (int i = tid; i < 128*128; i += 768){
    int ch = i & 127, k = i >> 7;
    int sw = (ch & 15) << 3;
    W2t[ch*128 + (k ^ sw)] = (_Float16)We2[k*128 + ch];
    Wxt[ch*128 + (k ^ sw)] = (_Float16)Wx1[k*128 + ch];
  }
  if (tid < 128) w1l_lds[tid] = (_Float16)We1[256*128 + tid];
  const int lane = tid & 63;
  const int w    = tid >> 6;
  const int q    = lane & 15;
  const int g    = lane >> 4;
  float be2r[8], bx1r[8], wx2r[8];
  #pragma unroll
  for (int nt = 0; nt < 8; nt++){
    int ch = nt*16 + q;
    be2r[nt] = be2[ch];
    bx1r[nt] = bx1[ch];
    wx2r[nt] = Wx2[ch];
  }
  const float bx2s = bx2[0];
  _Float16* mb = mbuf[w];
  __syncthreads();

  const int gw = blockIdx.x*12 + w;
  if (gw >= NW) return;

  half8 w1l_h[4];
  #pragma unroll
  for (int kk=0; kk<4; kk++)
    w1l_h[kk] = *(const half8*)&w1l_lds[kk*32 + g*8];

  // this lane's edge (dst-sorted)
  const unsigned sv = sdp[gw*64 + lane];
  const int esrc = (int)(sv >> 16);
  const int edst = (int)(sv & 0xffffu);
  float r0 = x[esrc*3+0] - x[edst*3+0];
  float r1 = x[esrc*3+1] - x[edst*3+1];
  float r2 = x[esrc*3+2] - x[edst*3+2];
  float d2 = r0*r0 + r1*r1 + r2*r2;

  // wave-boundary segment info
  const int first_dst = __shfl(edst, 0, 64);
  const int last_dst  = __shfl(edst, 63, 64);
  const bool prev_spill = (gw > 0)    && ((int)(sdp[gw*64 - 1] & 0xffffu) == first_dst);
  const bool next_spill = (gw < NW-1) && ((int)(sdp[gw*64 + 64] & 0xffffu) == last_dst);

  // per-mt MFMA-operand indices (hoisted)
  int srcq[4], dstq[4];
  __half2 d2h[4];
  #pragma unroll
  for (int mt=0; mt<4; mt++){
    srcq[mt] = __shfl(esrc, mt*16 + q, 64);
    dstq[mt] = __shfl(edst, mt*16 + q, 64);
    d2h[mt]  = __float2half2_rn(__shfl(d2, mt*16 + q, 64));
  }
  const __half2 one2 = __float2half2_rn(1.f);

  // cross-mt segment accumulator (channel pair 2*lane, 2*lane+1)
  float fa0 = 0.f, fa1 = 0.f;
  int   fdprev = first_dst;
  bool  seg_first = true;

  // prefetch double buffer (selected by compile-time mt&1 under full unroll)
  uint4 pa1[4], pa2[4], pb1[4], pb2[4];
  #pragma unroll
  for (int kk=0; kk<4; kk++){
    pa1[kk] = *(const uint4*)(g1 + (size_t)srcq[0]*DD + kk*32 + g*8);
    pa2[kk] = *(const uint4*)(g2 + (size_t)dstq[0]*DD + kk*32 + g*8);
  }

  #pragma unroll
  for (int mt=0; mt<4; mt++){
    uint4 (&cu1)[4] = (mt&1) ? pb1 : pa1;
    uint4 (&cu2)[4] = (mt&1) ? pb2 : pa2;
    uint4 (&nu1)[4] = (mt&1) ? pa1 : pb1;
    uint4 (&nu2)[4] = (mt&1) ? pa2 : pb2;
    if (mt < 3){
      #pragma unroll
      for (int kk=0; kk<4; kk++){
        nu1[kk] = *(const uint4*)(g1 + (size_t)srcq[mt+1]*DD + kk*32 + g*8);
        nu2[kk] = *(const uint4*)(g2 + (size_t)dstq[mt+1]*DD + kk*32 + g*8);
      }
    }

    // ---- phi_e L1: z = G1[src]+G2[dst]+d2*w1l, silu — packed f16 ----
    half8 a[4];
    #pragma unroll
    for (int kk=0; kk<4; kk++){
      uint4 w4 = __builtin_bit_cast(uint4, w1l_h[kk]);
      unsigned uu1[4] = {cu1[kk].x, cu1[kk].y, cu1[kk].z, cu1[kk].w};
      unsigned uu2[4] = {cu2[kk].x, cu2[kk].y, cu2[kk].z, cu2[kk].w};
      unsigned ww[4]  = {w4.x, w4.y, w4.z, w4.w};
      unsigned zz[4];
      #pragma unroll
      for (int p2=0; p2<4; p2++){
        __half2 z = __hadd2(__builtin_bit_cast(__half2, uu1[p2]),
                            __builtin_bit_cast(__half2, uu2[p2]));
        z = __hfma2(d2h[mt], __builtin_bit_cast(__half2, ww[p2]), z);
        __half2 e   = h2exp(__hneg2(z));
        __half2 den = __hadd2(e, one2);
        __half2 m   = __hmul2(z, h2rcp(den));
        zz[p2] = __builtin_bit_cast(unsigned, m);
      }
      uint4 t; t.x = zz[0]; t.y = zz[1]; t.z = zz[2]; t.w = zz[3];
      a[kk] = __builtin_bit_cast(half8, t);
    }

    // ---- phi_e layer 2 ----
    f32x4 acc2[8] = {};
    #pragma unroll
    for (int kk=0; kk<4; kk++){
      #pragma unroll
      for (int nt=0; nt<8; nt++){
        half8 b = *(const half8*)&W2t[(nt*16+q)*128 + ((kk*32+g*8) ^ (q<<3))];
        acc2[nt] = __builtin_amdgcn_mfma_f32_16x16x32_f16(a[kk], b, acc2[nt], 0,0,0);
      }
    }
    // silu -> m, transpose into mbuf
    #pragma unroll
    for (int nt=0; nt<8; nt++){
      #pragma unroll
      for (int r=0;r<4;r++){
        float s = silu_f(acc2[nt][r] + be2r[nt]);
        int el = 4*g + r;
        mb[el*128 + ((nt*16+q) ^ (el<<3))] = (_Float16)s;
      }
    }
    // ---- phi_x layer 1 ----
    f32x4 acc3[8] = {};
    #pragma unroll
    for (int kk=0; kk<4; kk++){
      half8 am = *(const half8*)&mb[q*128 + ((kk*32+g*8) ^ (q<<3))];
      #pragma unroll
      for (int nt=0; nt<8; nt++){
        half8 b = *(const half8*)&Wxt[(nt*16+q)*128 + ((kk*32+g*8) ^ (q<<3))];
        acc3[nt] = __builtin_amdgcn_mfma_f32_16x16x32_f16(am, b, acc3[nt], 0,0,0);
      }
    }
    // ---- coord_w reduce + per-edge cw store ----
    float part[4] = {0.f,0.f,0.f,0.f};
    #pragma unroll
    for (int nt=0; nt<8; nt++){
      #pragma unroll
      for (int r=0;r<4;r++)
        part[r] += silu_f(acc3[nt][r] + bx1r[nt]) * wx2r[nt];
    }
    #pragma unroll
    for (int m=1; m<16; m<<=1){
      #pragma unroll
      for (int r=0;r<4;r++) part[r] += __shfl_xor(part[r], m, 64);
    }
    {
      float cw = part[0];
      if (q==1) cw = part[1]; else if (q==2) cw = part[2]; else if (q==3) cw = part[3];
      if (q < 4) cwb[gw*64 + mt*16 + 4*g + q] = cw + bx2s;
    }
    // ---- segment-reduced agg flush ----
    {
      unsigned mv[16];
      #pragma unroll
      for (int e2=0; e2<16; e2++)
        mv[e2] = *(const unsigned*)&mb[e2*128 + ((2*lane) ^ (e2<<3))];
      int dv[16];
      #pragma unroll
      for (int e2=0; e2<16; e2++) dv[e2] = __shfl(edst, mt*16 + e2, 64);
      #pragma unroll
      for (int e2=0; e2<16; e2++){
        if (dv[e2] != fdprev){        // wave-uniform branch
          __half2 hv; hv.x = __float2half(fa0); hv.y = __float2half(fa1);
          _Float16* p = agg + (size_t)fdprev*DD + 2*lane;
          if (seg_first && prev_spill) atom_pk_f16(p, __builtin_bit_cast(unsigned, hv));
          else                         *(__half2*)p = hv;
          fa0 = 0.f; fa1 = 0.f; fdprev = dv[e2]; seg_first = false;
        }
        __half2 mvv = __builtin_bit_cast(__half2, mv[e2]);
        fa0 += __half2float(mvv.x);
        fa1 += __half2float(mvv.y);
      }
    }
  }
  // final flush
  {
    __half2 hv; hv.x = __float2half(fa0); hv.y = __float2half(fa1);
    _Float16* p = agg + (size_t)fdprev*DD + 2*lane;
    if ((seg_first && prev_spill) || next_spill) atom_pk_f16(p, __builtin_bit_cast(unsigned, hv));
    else                                         *(__half2*)p = hv;
  }
}

// ---------------------------------------------------------------------------
// FUSED: node update (blocks 0..624) + coordinate update (blocks 625..3124).
// ---------------------------------------------------------------------------
__global__ __launch_bounds__(256)
void k_nodecoord(const float* __restrict__ h, const _Float16* __restrict__ agg,
                 const _Float16* __restrict__ Wh1t, const _Float16* __restrict__ Wh2t,
                 const float* __restrict__ bh1, const float* __restrict__ bh2,
                 const float* __restrict__ gam, const float* __restrict__ bet,
                 const float* __restrict__ x, const float* __restrict__ cwb,
                 const unsigned* __restrict__ sdp, const int* __restrict__ counts,
                 const int* __restrict__ woff,
                 float* __restrict__ hout, float* __restrict__ xout)
{
  __shared__ __align__(16) _Float16 mbuf[4][16*128];  // 16 KB
  const int tid = threadIdx.x, lane = tid & 63, w = tid >> 6;

  if (blockIdx.x >= NN/64){
    // ---- coord part ----
    const int bidx = blockIdx.x - NN/64;
    const int sub = lane >> 4, j0 = lane & 15;
    const int n = (bidx*4 + w)*4 + sub;
    if (n >= NN) return;
    const int cnt = counts[n];
    const int s = woff[n] - cnt;      // woff is end-offset after scatter
    float xd0 = x[n*3+0], xd1 = x[n*3+1], xd2 = x[n*3+2];
    float s0=0.f, s1=0.f, s2=0.f;
    for (int j = j0; j < cnt; j += 16){
      int e = s + j;
      float cw = cwb[e];
      int src = (int)(sdp[e] >> 16);
      s0 += (x[src*3+0]-xd0)*cw;
      s1 += (x[src*3+1]-xd1)*cw;
      s2 += (x[src*3+2]-xd2)*cw;
    }
    #pragma unroll
    for (int m=1; m<16; m<<=1){
      s0 += __shfl_xor(s0, m, 64);
      s1 += __shfl_xor(s1, m, 64);
      s2 += __shfl_xor(s2, m, 64);
    }
    if (j0 == 0){
      float inv = __builtin_amdgcn_rcpf((float)(cnt > 1 ? cnt : 1));
      xout[n*3+0] = xd0 + s0*inv;
      xout[n*3+1] = xd1 + s1*inv;
      xout[n*3+2] = xd2 + s2*inv;
    }
    return;
  }

  // ---- node part ----
  const int q = lane & 15, g = lane >> 4;
  const int base = (blockIdx.x*4 + w) * 16;
  float bh1r[8], bh2r[8], gr[8], br[8];
  #pragma unroll
  for (int nt=0; nt<8; nt++){
    int ch = nt*16+q;
    bh1r[nt]=bh1[ch]; bh2r[nt]=bh2[ch]; gr[nt]=gam[ch]; br[nt]=bet[ch];
  }
  _Float16* mb = mbuf[w];

  f32x4 ac1[8] = {};
  #pragma unroll
  for (int kk=0; kk<8; kk++){
    half8 a;
    if (kk < 4){
      const float* rp = h + (size_t)(base+q)*DD + kk*32 + g*8;
      a = cvt_h8(*(const float4*)rp, *(const float4*)(rp+4));
    } else {
      a = *(const half8*)(agg + (size_t)(base+q)*DD + (kk-4)*32 + g*8);
    }
    #pragma unroll
    for (int nt=0; nt<8; nt++){
      half8 b = *(const half8*)&Wh1t[(nt*16+q)*256 + kk*32 + g*8];
      ac1[nt] = __builtin_amdgcn_mfma_f32_16x16x32_f16(a, b, ac1[nt], 0,0,0);
    }
  }
  #pragma unroll
  for (int nt=0; nt<8; nt++){
    #pragma unroll
    for (int r=0;r<4;r++){
      float s = silu_f(ac1[nt][r] + bh1r[nt]);
      int el = 4*g + r;
      mb[el*128 + ((nt*16+q) ^ (el<<3))] = (_Float16)s;
    }
  }
  f32x4 ac2[8] = {};
  #pragma unroll
  for (int kk=0; kk<4; kk++){
    half8 am = *(const half8*)&mb[q*128 + ((kk*32+g*8) ^ (q<<3))];
    #pragma unroll
    for (int nt=0; nt<8; nt++){
      half8 b = *(const half8*)&Wh2t[(nt*16+q)*128 + kk*32 + g*8];
      ac2[nt] = __builtin_amdgcn_mfma_f32_16x16x32_f16(am, b, ac2[nt], 0,0,0);
    }
  }
  #pragma unroll
  for (int r=0;r<4;r++){
    int node = base + 4*g + r;
    float hv[8]; float s1=0.f, s2=0.f;
    #pragma unroll
    for (int nt=0; nt<8; nt++){
      float v = ac2[nt][r] + bh2r[nt] + h[(size_t)node*DD + nt*16 + q];
      hv[nt]=v; s1 += v; s2 += v*v;
    }
    #pragma unroll
    for (int m=1;m<16;m<<=1){ s1 += __shfl_xor(s1,m,64); s2 += __shfl_xor(s2,m,64); }
    float mu  = s1 * (1.f/128.f);
    float var = s2 * (1.f/128.f) - mu*mu;
    float rs  = rsqrtf(var + 1e-5f);
    #pragma unroll
    for (int nt=0; nt<8; nt++)
      hout[(size_t)node*DD + nt*16 + q] = (hv[nt]-mu)*rs*gr[nt] + br[nt];
  }
}

extern "C" void kernel_launch(void* const* d_in, const int* in_sizes, int n_in,
                              void* d_out, int out_size, void* d_ws, size_t ws_size,
                              hipStream_t stream){
  const float* h   = (const float*)d_in[0];
  const float* x   = (const float*)d_in[1];
  const int*   ei  = (const int*)d_in[2];
  const float* We1 = (const float*)d_in[4];
  const float* be1 = (const float*)d_in[5];
  const float* We2 = (const float*)d_in[6];
  const float* be2 = (const float*)d_in[7];
  const float* Wx1 = (const float*)d_in[8];
  const float* bx1 = (const float*)d_in[9];
  const float* Wx2 = (const float*)d_in[10];
  const float* bx2 = (const float*)d_in[11];
  const float* Wh1 = (const float*)d_in[12];
  const float* bh1 = (const float*)d_in[13];
  const float* Wh2 = (const float*)d_in[14];
  const float* bh2 = (const float*)d_in[15];
  const float* gam = (const float*)d_in[16];
  const float* bet = (const float*)d_in[17];

  float* hout = (float*)d_out;
  float* xout = hout + (size_t)NN*DD;

  // ws layout (16B-aligned), ~36.4 MB
  char* p = (char*)d_ws;
  _Float16* agg  = (_Float16*)p;  p += (size_t)NN*DD*2;   // 10.24 MB
  _Float16* g1   = (_Float16*)p;  p += (size_t)NN*DD*2;   // 10.24 MB
  _Float16* g2   = (_Float16*)p;  p += (size_t)NN*DD*2;   // 10.24 MB
  int* counts    = (int*)p;       p += (size_t)NN*4;      // 0.16 MB
  int* woff      = (int*)p;       p += (size_t)NN*4;      // 0.16 MB
  unsigned* sdp  = (unsigned*)p;  p += (size_t)NE*4;      // 2.56 MB
  float* cwb     = (float*)p;     p += (size_t)NE*4;      // 2.56 MB
  _Float16* We1t = (_Float16*)p;  p += (size_t)128*256*2; // 64 KB
  _Float16* Wh1t = (_Float16*)p;  p += (size_t)128*256*2; // 64 KB
  _Float16* Wh2t = (_Float16*)p;  p += (size_t)128*128*2; // 32 KB
  int* bsum      = (int*)p;       p += 64*4;

  k_wt<<<128, 256, 0, stream>>>(We1, Wh1, Wh2, We1t, Wh1t, Wh2t, counts);
  k_hist<<<(NE+255)/256, 256, 0, stream>>>(ei, counts, (uint4*)agg);
  k_scanA<<<(NN+1023)/1024, 1024, 0, stream>>>(counts, woff, bsum);
  k_scanC<<<(NN+1023)/1024, 1024, 0, stream>>>(woff, bsum);
  k_scatgpre<<<NE/256 + NN/64, 256, 0, stream>>>(ei, woff, sdp, h, We1t, be1, g1, g2);
  egnn_edge<<<(NW + 11)/12, 768, 0, stream>>>(g1, g2, x, sdp, We1,
                                              We2, be2, Wx1, bx1, Wx2, bx2,
                                              agg, cwb);
  k_nodecoord<<<NN/64 + NN/16, 256, 0, stream>>>(h, agg, Wh1t, Wh2t, bh1, bh2,
                                                 gam, bet, x, cwb, sdp, counts,
                                                 woff, hout, xout);
}